// Round 4
// baseline (141.155 us; speedup 1.0000x reference)
//
#include <hip/hip_runtime.h>
#include <stdint.h>
#include <float.h>

using u64 = unsigned long long;
typedef float v2f __attribute__((ext_vector_type(2)));

constexpr int B_ = 2;
constexpr int NC = 512;
constexpr int NF = 8192;
constexpr int MT = 8192;

constexpr int TPB = 256;
constexpr int CFF = 32;    // fine j-chunks (256 j each)
constexpr int CCR = 128;   // coarse-rows j-chunks (64 j each)
constexpr int CCC = 8;     // coarse-cols j-chunks (64 j each)
constexpr int TAIL_BLOCKS = 196;   // 64 fine-rows + 64 fine-cols + 4 coarse-rows + 64 coarse-cols

#define DEVINL __device__ __forceinline__

// ---------------------------------------------------------------------------
// pairmin_phase: for its rows of P, min over a j-range of Q of
//   d = max((xx+qq) - 2*xy, 0)
// computed bit-exactly vs numpy fp32:
//   2*xy = ((2x0)q0 + (2x1)q1) + (2x2)q2  (power-of-2 scaling commutes with RN)
//   d    = fl(fl(xx+qq) - 2xy);  clamp once at pack time (monotone => exact).
//
// Broadcast mechanism history (the binding pipe each round):
//   R2: LDS broadcast read  -> CU-shared LDS unit serialized vs VALU (58.7us)
//   R3: v_readlane -> SGPR  -> VALU-pipe op + SGPR-write hazard stalls (86.9us)
//   R4: wave-uniform GLOBAL load ring -> VMEM pipe (parallel to VALU), 8-deep
//       register ring; each block re-reads only its ~3KB j-chunk (L1/L2-hit).
//       Inner loop is a pure VALU stream + 1 uniform load per j.
// R2t = row-pairs per thread (2 rows per pair packed in v2f for v_pk_*_f32).
// ---------------------------------------------------------------------------
template<bool ARGMIN, int R2t, int NJ>
DEVINL void pairmin_phase(const float* __restrict__ P, const float* __restrict__ Q,
                          int nP, int nQ, int b, int row_base, int j0,
                          int chunk, int nRowsTot,
                          u64* __restrict__ outPack, unsigned* __restrict__ outVal)
{
#pragma clang fp contract(off)
    const int tid = threadIdx.x;

    v2f tx0[R2t], tx1[R2t], tx2[R2t], txx[R2t], dbest[R2t];
    int jb[2 * R2t];
    #pragma unroll
    for (int r = 0; r < R2t; ++r) {
        const int row0 = row_base + tid + (2 * r) * TPB;
        const int row1 = row_base + tid + (2 * r + 1) * TPB;
        const float* p0 = P + ((size_t)b * nP + row0) * 3;
        const float* p1 = P + ((size_t)b * nP + row1) * 3;
        float a0 = p0[0], a1 = p0[1], a2 = p0[2];
        float e0 = p1[0], e1 = p1[1], e2 = p1[2];
        tx0[r] = v2f{2.0f * a0, 2.0f * e0};
        tx1[r] = v2f{2.0f * a1, 2.0f * e1};
        tx2[r] = v2f{2.0f * a2, 2.0f * e2};
        txx[r] = v2f{(a0*a0 + a1*a1) + a2*a2, (e0*e0 + e1*e1) + e2*e2};
        dbest[r] = v2f{FLT_MAX, FLT_MAX};
        jb[2 * r] = 0; jb[2 * r + 1] = 0;
    }

    const float* qbase = Q + (size_t)b * nQ * 3;

    // 8-deep wave-uniform load ring (VMEM pipe; ~230 wave-instrs of latency cover)
    float q0r[8], q1r[8], q2r[8];
    #pragma unroll
    for (int u = 0; u < 8; ++u) {
        const float* qp = qbase + (size_t)(j0 + u) * 3;
        q0r[u] = qp[0]; q1r[u] = qp[1]; q2r[u] = qp[2];
    }

    for (int jj = 0; jj < NJ; jj += 8) {
        #pragma unroll
        for (int u = 0; u < 8; ++u) {
            const float q0 = q0r[u], q1 = q1r[u], q2 = q2r[u];
            // issue next ring load (clamped to stay inside this j-chunk)
            int pj = jj + 8 + u;  pj = (pj < NJ) ? pj : (NJ - 1);
            const float* qp = qbase + (size_t)(j0 + pj) * 3;
            q0r[u] = qp[0]; q1r[u] = qp[1]; q2r[u] = qp[2];

            const float qq = (q0*q0 + q1*q1) + q2*q2;   // same fp32 chain as ref
            const int j = j0 + jj + u;
            #pragma unroll
            for (int r = 0; r < R2t; ++r) {
                v2f s = (tx0[r] * q0 + tx1[r] * q1) + tx2[r] * q2;  // == 2*xy
                v2f d = (txx[r] + qq) - s;                          // (xx+qq)-2xy
                if (ARGMIN) {
                    bool c0 = d.x < dbest[r].x;          // strict: first idx wins
                    bool c1 = d.y < dbest[r].y;
                    dbest[r].x = c0 ? d.x : dbest[r].x;
                    dbest[r].y = c1 ? d.y : dbest[r].y;
                    jb[2 * r]     = c0 ? j : jb[2 * r];
                    jb[2 * r + 1] = c1 ? j : jb[2 * r + 1];
                } else {
                    dbest[r] = __builtin_elementwise_min(dbest[r], d);
                }
            }
        }
    }

    const v2f vzero = {0.0f, 0.0f};
    const size_t o0 = (size_t)chunk * nRowsTot + (size_t)b * nP;
    #pragma unroll
    for (int r = 0; r < R2t; ++r) {
        v2f dcl = __builtin_elementwise_max(dbest[r], vzero);   // clamp once, exact
        const int row0 = row_base + tid + (2 * r) * TPB;
        const int row1 = row_base + tid + (2 * r + 1) * TPB;
        if (ARGMIN) {
            outPack[o0 + row0] = ((u64)__float_as_uint(dcl.x) << 32) | (unsigned)jb[2 * r];
            outPack[o0 + row1] = ((u64)__float_as_uint(dcl.y) << 32) | (unsigned)jb[2 * r + 1];
        } else {
            outVal[o0 + row0] = __float_as_uint(dcl.x);
            outVal[o0 + row1] = __float_as_uint(dcl.y);
        }
    }
}

// 512 identical-weight blocks (exactly 2 per CU), each runs 3 phases:
//   FR: fine-rows argmin, rows g*1024 (4/thr), j-chunk c*256 -> pfr[32][.]
//   FC: fine-cols value,  rows g*1024 (4/thr), j-chunk c*256 -> pfc[32][.]
//   one coarse slice: sub<128 -> coarse-rows (512 rows, 64 j)  -> pcr[128][.]
//                     sub>=128 -> coarse-cols (512 rows, 64 j) -> pcc[8][.]
// No LDS anywhere; no __syncthreads.
__global__ __launch_bounds__(TPB, 4) void pairmin_all(
    const float* __restrict__ coarse, const float* __restrict__ fine,
    const float* __restrict__ tgt,
    u64* __restrict__ pfr, unsigned* __restrict__ pfc,
    unsigned* __restrict__ pcr, unsigned* __restrict__ pcc,
    unsigned* __restrict__ counter)
{
    const int bx = blockIdx.x;
    if (bx == 0 && threadIdx.x == 0) *counter = 0;   // init for tail_all
    const int b   = bx >> 8;        // 0..1
    const int sub = bx & 255;
    const int g   = sub >> 5;       // 0..7   row-group (1024 rows)
    const int c   = sub & 31;       // 0..31  fine j-chunk (256 j)

    pairmin_phase<true, 2, 256>(fine, tgt, NF, MT, b, g * 1024, c * 256,
                                c, B_ * NF, pfr, nullptr);
    pairmin_phase<false, 2, 256>(tgt, fine, MT, NF, b, g * 1024, c * 256,
                                 c, B_ * MT, nullptr, pfc);
    if (sub < 128) {
        pairmin_phase<false, 1, 64>(coarse, tgt, NC, MT, b, 0, sub * 64,
                                    sub, B_ * NC, nullptr, pcr);
    } else {
        const int s2 = sub - 128;
        const int rg = s2 & 15;     // 0..15 row-group (512 rows)
        const int jc = s2 >> 4;     // 0..7  j-chunk (64 j)
        pairmin_phase<false, 1, 64>(tgt, coarse, MT, NC, b, rg * 512, jc * 64,
                                    jc, B_ * MT, nullptr, pcc);
    }
}

// ---------------------------------------------------------------------------
// tail_all: everything after the pairwise passes, one dispatch.
//  [0,  64) fine-rows: reduce 32 partials (u64 min = min d then min j), gather,
//           chamfer d1 sum, loss_ref/rot stats, wedge volumes (LDS halo).
//  [64,128) fine-cols value reduce (32 partials) -> d2f
//  [128,132) coarse-rows -> d1c (128 partials, unroll-16 for load ILP)
//  [132,196) coarse-cols -> d2c (8 partials)
// Each block writes its partial sums to bs[bx][16]; last-arriving block (via
// device-scope counter) reduces bs and writes the final scalar.
// ---------------------------------------------------------------------------
__global__ __launch_bounds__(TPB) void tail_all(
    const float* __restrict__ fine, const float* __restrict__ tgt,
    const u64* __restrict__ pfr, const unsigned* __restrict__ pfc,
    const unsigned* __restrict__ pcr, const unsigned* __restrict__ pcc,
    double* __restrict__ bs, unsigned* __restrict__ counter,
    float* __restrict__ out)
{
    __shared__ float sp[TPB + 2][3], yp[TPB + 2][3];
    __shared__ double redw[4][9];
    __shared__ double lred[4][13];
    __shared__ int lastflag;
    const int bx = blockIdx.x, tid = threadIdx.x;
    const int wave = tid >> 6, lane = tid & 63;

    double v_s = 0, v_d2f = 0, v_d1c = 0, v_d2c = 0, v_yd2 = 0, v_zs = 0, v_zt = 0;
    double vs = 0, vt = 0;
    int role_b = 0;

    if (bx < 64) {                              // ---- fine-rows ----
        const int base = bx * TPB;
        const int g = base + tid;
        const int b = base >> 13;  role_b = b;
        u64 best = pfr[g];
        #pragma unroll
        for (int cc = 1; cc < CFF; ++cc) {
            u64 p = pfr[(size_t)cc * (B_ * NF) + g];
            best = p < best ? p : best;
        }
        float d1 = __uint_as_float((unsigned)(best >> 32));
        int idx  = (int)(best & 0xffffffffULL);
        float s = sqrtf(fmaxf(d1, 1e-12f));
        const float* y  = tgt  + ((size_t)b * MT + idx) * 3;
        const float* sr = fine + (size_t)g * 3;
        float y0 = y[0],  y1 = y[1],  y2 = y[2];
        float s0 = sr[0], s1 = sr[1], s2 = sr[2];
        yp[tid][0] = y0; yp[tid][1] = y1; yp[tid][2] = y2;
        sp[tid][0] = s0; sp[tid][1] = s1; sp[tid][2] = s2;
        const int base_b = base & (NF - 1);
        if (tid < 2 && base_b + TPB + tid < NF) {        // halo rows
            int g2 = base + TPB + tid;
            u64 b2 = pfr[g2];
            #pragma unroll
            for (int cc = 1; cc < CFF; ++cc) {
                u64 p = pfr[(size_t)cc * (B_ * NF) + g2];
                b2 = p < b2 ? p : b2;
            }
            int i2 = (int)(b2 & 0xffffffffULL);
            const float* yh = tgt  + ((size_t)b * MT + i2) * 3;
            const float* sh = fine + (size_t)g2 * 3;
            #pragma unroll
            for (int k = 0; k < 3; ++k) { yp[TPB + tid][k] = yh[k]; sp[TPB + tid][k] = sh[k]; }
        }
        __syncthreads();
        v_s = s;
        float yd = s1 - y1;
        v_yd2 = (double)(yd * yd);
        v_zs  = (double)(s2 * s2);
        v_zt  = (double)(y2 * y2);
        int rb = base_b + tid;
        if (rb <= NF - 3) {          // same f32 exprs as the verified R3 kernel
            {
                const float* a = sp[tid]; const float* c2 = sp[tid+1]; const float* e = sp[tid+2];
                float c0 = a[1]*c2[2] - a[2]*c2[1];
                float c1 = a[2]*c2[0] - a[0]*c2[2];
                float c2v = a[0]*c2[1] - a[1]*c2[0];
                vs = (double)(c0*e[0] + c1*e[1] + c2v*e[2]);
            }
            {
                const float* a = yp[tid]; const float* c2 = yp[tid+1]; const float* e = yp[tid+2];
                float c0 = a[1]*c2[2] - a[2]*c2[1];
                float c1 = a[2]*c2[0] - a[0]*c2[2];
                float c2v = a[0]*c2[1] - a[1]*c2[0];
                vt = (double)(c0*e[0] + c1*e[1] + c2v*e[2]);
            }
        }
    } else if (bx < 128) {                      // ---- fine-cols ----
        const int g = (bx - 64) * TPB + tid;
        unsigned best = pfc[g];
        #pragma unroll
        for (int cc = 1; cc < CFF; ++cc) best = min(best, pfc[(size_t)cc * (B_ * MT) + g]);
        v_d2f = (double)sqrtf(fmaxf(__uint_as_float(best), 1e-12f));
    } else if (bx < 132) {                      // ---- coarse-rows ----
        const int g = (bx - 128) * TPB + tid;
        unsigned best = pcr[g];
        #pragma unroll 16
        for (int cc = 1; cc < CCR; ++cc) best = min(best, pcr[(size_t)cc * (B_ * NC) + g]);
        v_d1c = (double)sqrtf(fmaxf(__uint_as_float(best), 1e-12f));
    } else {                                    // ---- coarse-cols ----
        const int g = (bx - 132) * TPB + tid;
        unsigned best = pcc[g];
        #pragma unroll
        for (int cc = 1; cc < CCC; ++cc) best = min(best, pcc[(size_t)cc * (B_ * MT) + g]);
        v_d2c = (double)sqrtf(fmaxf(__uint_as_float(best), 1e-12f));
    }

    // block reduce 9 values
    double r9[9] = {v_s, v_d2f, v_d1c, v_d2c, v_yd2, v_zs, v_zt, vs, vt};
    for (int o = 32; o; o >>= 1) {
        #pragma unroll
        for (int k = 0; k < 9; ++k) r9[k] += __shfl_down(r9[k], o);
    }
    if (lane == 0) {
        #pragma unroll
        for (int k = 0; k < 9; ++k) redw[wave][k] = r9[k];
    }
    __syncthreads();
    if (tid == 0) {
        double t9[9];
        #pragma unroll
        for (int k = 0; k < 9; ++k)
            t9[k] = redw[0][k] + redw[1][k] + redw[2][k] + redw[3][k];
        double* o = bs + (size_t)bx * 16;
        #pragma unroll
        for (int k = 0; k < 16; ++k) o[k] = 0.0;
        o[0] = t9[0]; o[1] = t9[1]; o[2] = t9[2]; o[3] = t9[3]; o[4] = t9[4];
        o[5 + role_b]  = t9[5];   // zs
        o[7 + role_b]  = t9[6];   // zt
        o[9 + role_b]  = t9[7];   // vs
        o[11 + role_b] = t9[8];   // vt
        __threadfence();
        unsigned old = atomicAdd(counter, 1u);
        lastflag = (old == TAIL_BLOCKS - 1);
    }
    __syncthreads();
    if (!lastflag) return;

    // ---- final combine (last block only) ----
    __threadfence();
    double c13[13];
    if (tid < TAIL_BLOCKS) {
        const double* p = bs + (size_t)tid * 16;
        #pragma unroll
        for (int k = 0; k < 13; ++k) c13[k] = p[k];
    } else {
        #pragma unroll
        for (int k = 0; k < 13; ++k) c13[k] = 0.0;
    }
    for (int o = 32; o; o >>= 1) {
        #pragma unroll
        for (int k = 0; k < 13; ++k) c13[k] += __shfl_down(c13[k], o);
    }
    if (lane == 0) {
        #pragma unroll
        for (int k = 0; k < 13; ++k) lred[wave][k] = c13[k];
    }
    __syncthreads();
    if (tid == 0) {
        double S[13];
        #pragma unroll
        for (int k = 0; k < 13; ++k)
            S[k] = lred[0][k] + lred[1][k] + lred[2][k] + lred[3][k];
        double m_d1f = S[0] / (double)(B_ * NF);
        double m_d2f = S[1] / (double)(B_ * MT);
        double m_d1c = S[2] / (double)(B_ * NC);
        double m_d2c = S[3] / (double)(B_ * MT);
        double loss_align_fine   = 0.5 * (m_d1f + m_d2f);
        double loss_align_coarse = 0.5 * (m_d1c + m_d2c);
        double loss_ref = S[4] / (double)(B_ * NF);
        double loss_rot = 0.0, loss_geo = 0.0;
        for (int b = 0; b < B_; ++b) {
            double dn = sqrt(S[5 + b]) - sqrt(S[7 + b]);
            loss_rot += dn * dn;
            double dv = (S[9 + b] - S[11 + b]) / 6.0;
            loss_geo += dv * dv;
        }
        loss_rot /= (double)B_;
        loss_geo /= (double)B_;
        out[0] = (float)(loss_rot + loss_ref + loss_align_coarse + loss_align_fine + loss_geo);
    }
}

extern "C" void kernel_launch(void* const* d_in, const int* in_sizes, int n_in,
                              void* d_out, int out_size, void* d_ws, size_t ws_size,
                              hipStream_t stream)
{
    const float* src_coarse = (const float*)d_in[0];
    const float* src_fine   = (const float*)d_in[1];
    const float* tgt        = (const float*)d_in[2];
    float* out = (float*)d_out;
    char*  ws  = (char*)d_ws;

    // ws layout (bytes), everything written before read — no init needed:
    //   [0,        4194304)  u64 pfr[32][16384]   fine-rows (d,j) partials
    //   [4194304,  6291456)  u32 pfc[32][16384]   fine-cols value partials
    //   [6291456,  6815744)  u32 pcr[128][1024]   coarse-rows value partials
    //   [6815744,  7340032)  u32 pcc[8][16384]    coarse-cols value partials
    //   [7340032,  7365120)  double bs[196][16]   per-tail-block sums
    //   [7365120,  7365124)  u32 counter          (zeroed by pairmin_all blk 0)
    u64*      pfr     = (u64*)(ws);
    unsigned* pfc     = (unsigned*)(ws + 4194304);
    unsigned* pcr     = (unsigned*)(ws + 6291456);
    unsigned* pcc     = (unsigned*)(ws + 6815744);
    double*   bs      = (double*)(ws + 7340032);
    unsigned* counter = (unsigned*)(ws + 7365120);

    pairmin_all<<<dim3(512), TPB, 0, stream>>>(
        src_coarse, src_fine, tgt, pfr, pfc, pcr, pcc, counter);
    tail_all<<<dim3(TAIL_BLOCKS), TPB, 0, stream>>>(
        src_fine, tgt, pfr, pfc, pcr, pcc, bs, counter, out);
}

// Round 5
// 120.345 us; speedup vs baseline: 1.1729x; 1.1729x over previous
//
#include <hip/hip_runtime.h>
#include <stdint.h>
#include <float.h>

using u64 = unsigned long long;
typedef float v2f __attribute__((ext_vector_type(2)));

constexpr int B_ = 2;
constexpr int NC = 512;
constexpr int NF = 8192;
constexpr int MT = 8192;

constexpr int TPB = 256;
constexpr int CFF = 32;    // fine j-chunks (256 j each)
constexpr int CCR = 128;   // coarse-rows j-chunks (64 j each)
constexpr int CCC = 8;     // coarse-cols j-chunks (64 j each)
constexpr int TAIL_BLOCKS = 196;   // 64 fine-rows + 64 fine-cols + 4 coarse-rows + 64 coarse-cols

#define DEVINL __device__ __forceinline__

// ---------------------------------------------------------------------------
// pairmin_phase: for its rows of P, min over a j-range of Q of
//   d = max((xx+qq) - 2*xy, 0)
// computed bit-exactly vs numpy fp32:
//   2*xy = ((2x0)q0 + (2x1)q1) + (2x2)q2  (power-of-2 scaling commutes with RN)
//   d    = fl(fl(xx+qq) - 2xy);  clamp once at pack time (monotone => exact).
//
// Mechanism history: LDS broadcast (R2, 58.7us, best) / readlane (R3, 86.9,
// VALU+SGPR hazard) / scalar-load ring (R4, 78, lgkmcnt drains). Conclusion:
// broadcast cost per j is ~fixed (~12cyc LDS return per wave), so AMORTIZE it:
// R2t=4 => 8 rows/thread => per wave per j: 12 LDS-cyc vs ~104 VALU-cyc
// (argmin) — LDS duty ~40-60% on a mixed CU instead of R2's ~100%. j-chunk
// (256) == tile => stage once, no mid-loop barriers.
// R2t = row-pairs per thread (2 rows per pair packed in v2f -> v_pk_*_f32).
// NJ = j-chunk length (256 fine, 64 coarse).
// ---------------------------------------------------------------------------
template<bool ARGMIN, int R2t, int NJ>
DEVINL void pairmin_phase(const float* __restrict__ P, const float* __restrict__ Q,
                          int nP, int nQ, int b, int row_base, int j0,
                          int chunk, int nRowsTot,
                          u64* __restrict__ outPack, unsigned* __restrict__ outVal,
                          float4* tile)
{
#pragma clang fp contract(off)
    const int tid = threadIdx.x;

    v2f tx0[R2t], tx1[R2t], tx2[R2t], txx[R2t], dbest[R2t];
    int jb[2 * R2t];
    #pragma unroll
    for (int r = 0; r < R2t; ++r) {
        const int row0 = row_base + tid + (2 * r) * TPB;
        const int row1 = row_base + tid + (2 * r + 1) * TPB;
        const float* p0 = P + ((size_t)b * nP + row0) * 3;
        const float* p1 = P + ((size_t)b * nP + row1) * 3;
        float a0 = p0[0], a1 = p0[1], a2 = p0[2];
        float e0 = p1[0], e1 = p1[1], e2 = p1[2];
        tx0[r] = v2f{2.0f * a0, 2.0f * e0};
        tx1[r] = v2f{2.0f * a1, 2.0f * e1};
        tx2[r] = v2f{2.0f * a2, 2.0f * e2};
        txx[r] = v2f{(a0*a0 + a1*a1) + a2*a2, (e0*e0 + e1*e1) + e2*e2};
        dbest[r] = v2f{FLT_MAX, FLT_MAX};
        jb[2 * r] = 0; jb[2 * r + 1] = 0;
    }

    __syncthreads();                 // protect tile reuse across phases
    if (tid < NJ) {                  // stage whole j-chunk once (qq in .w)
        const float* q = Q + ((size_t)b * nQ + j0 + tid) * 3;
        float q0 = q[0], q1 = q[1], q2 = q[2];
        tile[tid] = make_float4(q0, q1, q2, (q0*q0 + q1*q1) + q2*q2);
    }
    __syncthreads();

    auto PROC = [&](const float4 qv, const int j) {
#pragma clang fp contract(off)
        #pragma unroll
        for (int r = 0; r < R2t; ++r) {
            v2f s = (tx0[r] * qv.x + tx1[r] * qv.y) + tx2[r] * qv.z;  // == 2*xy
            v2f d = (txx[r] + qv.w) - s;                              // (xx+qq)-2xy
            if (ARGMIN) {
                bool c0 = d.x < dbest[r].x;          // strict: first idx wins
                bool c1 = d.y < dbest[r].y;
                dbest[r].x = c0 ? d.x : dbest[r].x;
                dbest[r].y = c1 ? d.y : dbest[r].y;
                jb[2 * r]     = c0 ? j : jb[2 * r];
                jb[2 * r + 1] = c1 ? j : jb[2 * r + 1];
            } else {
                dbest[r] = __builtin_elementwise_min(dbest[r], d);
            }
        }
    };

    float4 qa[4], qb[4];
    #pragma unroll
    for (int u = 0; u < 4; ++u) qa[u] = tile[u];
    for (int jj = 0; jj < NJ; jj += 8) {            // depth-4 ping-pong reads
        #pragma unroll
        for (int u = 0; u < 4; ++u) qb[u] = tile[jj + 4 + u];
        #pragma unroll
        for (int u = 0; u < 4; ++u) PROC(qa[u], j0 + jj + u);
        #pragma unroll
        for (int u = 0; u < 4; ++u) qa[u] = tile[(jj + 8 + u) & (NJ - 1)];
        #pragma unroll
        for (int u = 0; u < 4; ++u) PROC(qb[u], j0 + jj + 4 + u);
    }

    const v2f vzero = {0.0f, 0.0f};
    const size_t o0 = (size_t)chunk * nRowsTot + (size_t)b * nP;
    #pragma unroll
    for (int r = 0; r < R2t; ++r) {
        v2f dcl = __builtin_elementwise_max(dbest[r], vzero);   // clamp once, exact
        const int row0 = row_base + tid + (2 * r) * TPB;
        const int row1 = row_base + tid + (2 * r + 1) * TPB;
        if (ARGMIN) {
            outPack[o0 + row0] = ((u64)__float_as_uint(dcl.x) << 32) | (unsigned)jb[2 * r];
            outPack[o0 + row1] = ((u64)__float_as_uint(dcl.y) << 32) | (unsigned)jb[2 * r + 1];
        } else {
            outVal[o0 + row0] = __float_as_uint(dcl.x);
            outVal[o0 + row1] = __float_as_uint(dcl.y);
        }
    }
}

// 512 blocks, exactly 2 per CU (launch_bounds(256,2): no spill, 8 waves/CU):
//  [0,  256): FR — fine-rows argmin, 2048 rows (8/thr), 256-j chunk -> pfr[32][.]
//             + coarse-rows slice (512 rows, 2/thr, 64 j)           -> pcr[128][.]
//  [256,512): FC — fine-cols value, 2048 tgt rows (8/thr), 256-j    -> pfc[32][.]
//             + coarse-cols slice (512 rows, 2/thr, 64 j)           -> pcc[8][.]
// FR blocks first, FC second: round-robin XCD dispatch pairs one FR + one FC
// per CU, mixing the VALU-heavy and LDS-heavy phases on each LDS unit.
__global__ __launch_bounds__(TPB, 2) void pairmin_all(
    const float* __restrict__ coarse, const float* __restrict__ fine,
    const float* __restrict__ tgt,
    u64* __restrict__ pfr, unsigned* __restrict__ pfc,
    unsigned* __restrict__ pcr, unsigned* __restrict__ pcc,
    unsigned* __restrict__ counter)
{
    __shared__ float4 tile[256];
    const int bx = blockIdx.x;
    if (bx == 0 && threadIdx.x == 0) *counter = 0;   // init for tail_all
    if (bx < 256) {
        const int b = bx >> 7, g = (bx >> 5) & 3, c = bx & 31;
        pairmin_phase<true, 4, 256>(fine, tgt, NF, MT, b, g * 2048, c * 256,
                                    c, B_ * NF, pfr, nullptr, tile);
        // coarse-rows slice: b = bx>>7, j-chunk = bx&127 (64 j), rows 0..511
        pairmin_phase<false, 1, 64>(coarse, tgt, NC, MT, bx >> 7, 0, (bx & 127) * 64,
                                    bx & 127, B_ * NC, nullptr, pcr, tile);
    } else {
        const int i = bx - 256;
        const int b = i >> 7, g = (i >> 5) & 3, c = i & 31;
        pairmin_phase<false, 4, 256>(tgt, fine, MT, NF, b, g * 2048, c * 256,
                                     c, B_ * MT, nullptr, pfc, tile);
        // coarse-cols slice: b = i>>7, rowgroup = (i>>3)&15 (512 rows), jc = i&7
        pairmin_phase<false, 1, 64>(tgt, coarse, MT, NC, i >> 7, ((i >> 3) & 15) * 512,
                                    (i & 7) * 64, i & 7, B_ * MT, nullptr, pcc, tile);
    }
}

// ---------------------------------------------------------------------------
// tail_all: everything after the pairwise passes, one dispatch. (unchanged)
//  [0,  64) fine-rows: reduce 32 partials (u64 min = min d then min j), gather,
//           chamfer d1 sum, loss_ref/rot stats, wedge volumes (LDS halo).
//  [64,128) fine-cols value reduce (32 partials) -> d2f
//  [128,132) coarse-rows -> d1c (128 partials, unroll-16 for load ILP)
//  [132,196) coarse-cols -> d2c (8 partials)
// Each block writes its partial sums to bs[bx][16]; last-arriving block (via
// device-scope counter) reduces bs and writes the final scalar.
// ---------------------------------------------------------------------------
__global__ __launch_bounds__(TPB) void tail_all(
    const float* __restrict__ fine, const float* __restrict__ tgt,
    const u64* __restrict__ pfr, const unsigned* __restrict__ pfc,
    const unsigned* __restrict__ pcr, const unsigned* __restrict__ pcc,
    double* __restrict__ bs, unsigned* __restrict__ counter,
    float* __restrict__ out)
{
    __shared__ float sp[TPB + 2][3], yp[TPB + 2][3];
    __shared__ double redw[4][9];
    __shared__ double lred[4][13];
    __shared__ int lastflag;
    const int bx = blockIdx.x, tid = threadIdx.x;
    const int wave = tid >> 6, lane = tid & 63;

    double v_s = 0, v_d2f = 0, v_d1c = 0, v_d2c = 0, v_yd2 = 0, v_zs = 0, v_zt = 0;
    double vs = 0, vt = 0;
    int role_b = 0;

    if (bx < 64) {                              // ---- fine-rows ----
        const int base = bx * TPB;
        const int g = base + tid;
        const int b = base >> 13;  role_b = b;
        u64 best = pfr[g];
        #pragma unroll
        for (int cc = 1; cc < CFF; ++cc) {
            u64 p = pfr[(size_t)cc * (B_ * NF) + g];
            best = p < best ? p : best;
        }
        float d1 = __uint_as_float((unsigned)(best >> 32));
        int idx  = (int)(best & 0xffffffffULL);
        float s = sqrtf(fmaxf(d1, 1e-12f));
        const float* y  = tgt  + ((size_t)b * MT + idx) * 3;
        const float* sr = fine + (size_t)g * 3;
        float y0 = y[0],  y1 = y[1],  y2 = y[2];
        float s0 = sr[0], s1 = sr[1], s2 = sr[2];
        yp[tid][0] = y0; yp[tid][1] = y1; yp[tid][2] = y2;
        sp[tid][0] = s0; sp[tid][1] = s1; sp[tid][2] = s2;
        const int base_b = base & (NF - 1);
        if (tid < 2 && base_b + TPB + tid < NF) {        // halo rows
            int g2 = base + TPB + tid;
            u64 b2 = pfr[g2];
            #pragma unroll
            for (int cc = 1; cc < CFF; ++cc) {
                u64 p = pfr[(size_t)cc * (B_ * NF) + g2];
                b2 = p < b2 ? p : b2;
            }
            int i2 = (int)(b2 & 0xffffffffULL);
            const float* yh = tgt  + ((size_t)b * MT + i2) * 3;
            const float* sh = fine + (size_t)g2 * 3;
            #pragma unroll
            for (int k = 0; k < 3; ++k) { yp[TPB + tid][k] = yh[k]; sp[TPB + tid][k] = sh[k]; }
        }
        __syncthreads();
        v_s = s;
        float yd = s1 - y1;
        v_yd2 = (double)(yd * yd);
        v_zs  = (double)(s2 * s2);
        v_zt  = (double)(y2 * y2);
        int rb = base_b + tid;
        if (rb <= NF - 3) {          // same f32 exprs as the verified R3 kernel
            {
                const float* a = sp[tid]; const float* c2 = sp[tid+1]; const float* e = sp[tid+2];
                float c0 = a[1]*c2[2] - a[2]*c2[1];
                float c1 = a[2]*c2[0] - a[0]*c2[2];
                float c2v = a[0]*c2[1] - a[1]*c2[0];
                vs = (double)(c0*e[0] + c1*e[1] + c2v*e[2]);
            }
            {
                const float* a = yp[tid]; const float* c2 = yp[tid+1]; const float* e = yp[tid+2];
                float c0 = a[1]*c2[2] - a[2]*c2[1];
                float c1 = a[2]*c2[0] - a[0]*c2[2];
                float c2v = a[0]*c2[1] - a[1]*c2[0];
                vt = (double)(c0*e[0] + c1*e[1] + c2v*e[2]);
            }
        }
    } else if (bx < 128) {                      // ---- fine-cols ----
        const int g = (bx - 64) * TPB + tid;
        unsigned best = pfc[g];
        #pragma unroll
        for (int cc = 1; cc < CFF; ++cc) best = min(best, pfc[(size_t)cc * (B_ * MT) + g]);
        v_d2f = (double)sqrtf(fmaxf(__uint_as_float(best), 1e-12f));
    } else if (bx < 132) {                      // ---- coarse-rows ----
        const int g = (bx - 128) * TPB + tid;
        unsigned best = pcr[g];
        #pragma unroll 16
        for (int cc = 1; cc < CCR; ++cc) best = min(best, pcr[(size_t)cc * (B_ * NC) + g]);
        v_d1c = (double)sqrtf(fmaxf(__uint_as_float(best), 1e-12f));
    } else {                                    // ---- coarse-cols ----
        const int g = (bx - 132) * TPB + tid;
        unsigned best = pcc[g];
        #pragma unroll
        for (int cc = 1; cc < CCC; ++cc) best = min(best, pcc[(size_t)cc * (B_ * MT) + g]);
        v_d2c = (double)sqrtf(fmaxf(__uint_as_float(best), 1e-12f));
    }

    // block reduce 9 values
    double r9[9] = {v_s, v_d2f, v_d1c, v_d2c, v_yd2, v_zs, v_zt, vs, vt};
    for (int o = 32; o; o >>= 1) {
        #pragma unroll
        for (int k = 0; k < 9; ++k) r9[k] += __shfl_down(r9[k], o);
    }
    if (lane == 0) {
        #pragma unroll
        for (int k = 0; k < 9; ++k) redw[wave][k] = r9[k];
    }
    __syncthreads();
    if (tid == 0) {
        double t9[9];
        #pragma unroll
        for (int k = 0; k < 9; ++k)
            t9[k] = redw[0][k] + redw[1][k] + redw[2][k] + redw[3][k];
        double* o = bs + (size_t)bx * 16;
        #pragma unroll
        for (int k = 0; k < 16; ++k) o[k] = 0.0;
        o[0] = t9[0]; o[1] = t9[1]; o[2] = t9[2]; o[3] = t9[3]; o[4] = t9[4];
        o[5 + role_b]  = t9[5];   // zs
        o[7 + role_b]  = t9[6];   // zt
        o[9 + role_b]  = t9[7];   // vs
        o[11 + role_b] = t9[8];   // vt
        __threadfence();
        unsigned old = atomicAdd(counter, 1u);
        lastflag = (old == TAIL_BLOCKS - 1);
    }
    __syncthreads();
    if (!lastflag) return;

    // ---- final combine (last block only) ----
    __threadfence();
    double c13[13];
    if (tid < TAIL_BLOCKS) {
        const double* p = bs + (size_t)tid * 16;
        #pragma unroll
        for (int k = 0; k < 13; ++k) c13[k] = p[k];
    } else {
        #pragma unroll
        for (int k = 0; k < 13; ++k) c13[k] = 0.0;
    }
    for (int o = 32; o; o >>= 1) {
        #pragma unroll
        for (int k = 0; k < 13; ++k) c13[k] += __shfl_down(c13[k], o);
    }
    if (lane == 0) {
        #pragma unroll
        for (int k = 0; k < 13; ++k) lred[wave][k] = c13[k];
    }
    __syncthreads();
    if (tid == 0) {
        double S[13];
        #pragma unroll
        for (int k = 0; k < 13; ++k)
            S[k] = lred[0][k] + lred[1][k] + lred[2][k] + lred[3][k];
        double m_d1f = S[0] / (double)(B_ * NF);
        double m_d2f = S[1] / (double)(B_ * MT);
        double m_d1c = S[2] / (double)(B_ * NC);
        double m_d2c = S[3] / (double)(B_ * MT);
        double loss_align_fine   = 0.5 * (m_d1f + m_d2f);
        double loss_align_coarse = 0.5 * (m_d1c + m_d2c);
        double loss_ref = S[4] / (double)(B_ * NF);
        double loss_rot = 0.0, loss_geo = 0.0;
        for (int b = 0; b < B_; ++b) {
            double dn = sqrt(S[5 + b]) - sqrt(S[7 + b]);
            loss_rot += dn * dn;
            double dv = (S[9 + b] - S[11 + b]) / 6.0;
            loss_geo += dv * dv;
        }
        loss_rot /= (double)B_;
        loss_geo /= (double)B_;
        out[0] = (float)(loss_rot + loss_ref + loss_align_coarse + loss_align_fine + loss_geo);
    }
}

extern "C" void kernel_launch(void* const* d_in, const int* in_sizes, int n_in,
                              void* d_out, int out_size, void* d_ws, size_t ws_size,
                              hipStream_t stream)
{
    const float* src_coarse = (const float*)d_in[0];
    const float* src_fine   = (const float*)d_in[1];
    const float* tgt        = (const float*)d_in[2];
    float* out = (float*)d_out;
    char*  ws  = (char*)d_ws;

    // ws layout (bytes), everything written before read — no init needed:
    //   [0,        4194304)  u64 pfr[32][16384]   fine-rows (d,j) partials
    //   [4194304,  6291456)  u32 pfc[32][16384]   fine-cols value partials
    //   [6291456,  6815744)  u32 pcr[128][1024]   coarse-rows value partials
    //   [6815744,  7340032)  u32 pcc[8][16384]    coarse-cols value partials
    //   [7340032,  7365120)  double bs[196][16]   per-tail-block sums
    //   [7365120,  7365124)  u32 counter          (zeroed by pairmin_all blk 0)
    u64*      pfr     = (u64*)(ws);
    unsigned* pfc     = (unsigned*)(ws + 4194304);
    unsigned* pcr     = (unsigned*)(ws + 6291456);
    unsigned* pcc     = (unsigned*)(ws + 6815744);
    double*   bs      = (double*)(ws + 7340032);
    unsigned* counter = (unsigned*)(ws + 7365120);

    pairmin_all<<<dim3(512), TPB, 0, stream>>>(
        src_coarse, src_fine, tgt, pfr, pfc, pcr, pcc, counter);
    tail_all<<<dim3(TAIL_BLOCKS), TPB, 0, stream>>>(
        src_fine, tgt, pfr, pfc, pcr, pcc, bs, counter, out);
}